// Round 2
// baseline (477.484 us; speedup 1.0000x reference)
//
#include <hip/hip_runtime.h>
#include <stdint.h>

#define HH 512
#define WW 512
#define CIN 64
#define COUT 128
#define NB 4
#define BX 128          // x-sites per conv block
#define NCOL (BX + 2)   // 130 staged columns (halo)
#define CPAD 72         // padded channel dim in LDS

typedef __bf16 bf16x8 __attribute__((ext_vector_type(8)));
typedef __bf16 bf16x4 __attribute__((ext_vector_type(4)));
typedef float f32x4 __attribute__((ext_vector_type(4)));

__device__ __forceinline__ unsigned short f2bf(float f) {
    union { float f; uint32_t u; } v; v.f = f;
    uint32_t u = v.u;
    u += 0x7fffu + ((u >> 16) & 1u);   // RNE
    return (unsigned short)(u >> 16);
}

// Wt2 layout: [(k>>3)][co][k&7] bf16, k = (ky*3+kx)*64 + ci  (576 x 128)
__global__ void wt_transform(const float* __restrict__ w, unsigned short* __restrict__ wt2) {
    int tid = blockIdx.x * 256 + threadIdx.x;
    if (tid >= COUT * 576) return;
    int co = tid / 576;
    int k  = tid - co * 576;
    int off = k >> 6;
    int ci  = k & 63;
    int ky = off / 3;
    int kx = off - ky * 3;
    float val = w[((co * CIN + ci) * 3 + ky) * 3 + kx];
    wt2[(size_t)(k >> 3) * (COUT * 8) + co * 8 + (k & 7)] = f2bf(val);
}

// dense ws: [B][H][W][CIN] f32 (NHWC). One lane per (point, channel).
__global__ void scatter_kernel(const float* __restrict__ feat,
                               const int* __restrict__ coors,
                               float* __restrict__ dense, int npts) {
    int t = blockIdx.x * 256 + threadIdx.x;
    int p = t >> 6;
    int c = t & 63;
    if (p >= npts) return;
    int b = coors[p * 3 + 0];
    int y = coors[p * 3 + 1];
    int x = coors[p * 3 + 2];
    atomicAdd(&dense[(((size_t)b * HH + y) * WW + x) * CIN + c], feat[(size_t)p * CIN + c]);
}

// Block: batch b, row y, 128 x-sites, all 128 co. 4 waves, each 64co x 64sites.
// GEMM: out[co][site] = sum_k Wt[co][k] * patch[k][site], K = 576.
__global__ __launch_bounds__(256) void conv_kernel(
        const float* __restrict__ dense,
        const __bf16* __restrict__ wt2,
        float* __restrict__ out) {
    __shared__ __align__(16) __bf16 patch[3 * NCOL * CPAD];

    const int bid = blockIdx.x;
    const int x0 = (bid & 3) * BX;
    const int y  = (bid >> 2) & 511;
    const int b  = bid >> 11;
    const int tid = threadIdx.x;

    // stage 3 rows x 130 cols x 64 ch, f32 -> bf16 (v_cvt), zero halo
    for (int i = tid; i < 3 * NCOL * 16; i += 256) {
        int row = i / (NCOL * 16);
        int rem = i - row * (NCOL * 16);
        int col = rem >> 4;
        int c4  = rem & 15;
        int yy = y - 1 + row;
        int xx = x0 - 1 + col;
        float4 v = make_float4(0.f, 0.f, 0.f, 0.f);
        if ((unsigned)yy < HH && (unsigned)xx < WW) {
            v = *reinterpret_cast<const float4*>(
                &dense[(((size_t)b * HH + yy) * WW + xx) * CIN + (c4 << 2)]);
        }
        bf16x4 s = { (__bf16)v.x, (__bf16)v.y, (__bf16)v.z, (__bf16)v.w };
        *reinterpret_cast<bf16x4*>(&patch[(row * NCOL + col) * CPAD + (c4 << 2)]) = s;
    }
    __syncthreads();

    const int wave = tid >> 6;
    const int lane = tid & 63;
    const int lhi = lane >> 4;   // 0..3
    const int llo = lane & 15;
    const int co_base   = (wave >> 1) * 64;   // wave owns 64 co
    const int site_base = (wave & 1) * 64;    // and 64 sites

    f32x4 acc[4][4];
    #pragma unroll
    for (int m = 0; m < 4; ++m)
        #pragma unroll
        for (int n = 0; n < 4; ++n)
            acc[m][n] = (f32x4){0.f, 0.f, 0.f, 0.f};

    #pragma unroll
    for (int off = 0; off < 9; ++off) {
        const int ky = off / 3;
        const int kx = off - ky * 3;
        #pragma unroll
        for (int ch = 0; ch < 2; ++ch) {
            // A fragments (weights), L2-resident: lane co = co_base+m*16+llo, k chunk lhi
            const __bf16* abase = wt2 + (size_t)(off * 8 + ch * 4 + lhi) * (COUT * 8);
            bf16x8 a[4];
            #pragma unroll
            for (int m = 0; m < 4; ++m)
                a[m] = *reinterpret_cast<const bf16x8*>(&abase[(co_base + m * 16 + llo) * 8]);
            #pragma unroll
            for (int n = 0; n < 4; ++n) {
                bf16x8 bb = *reinterpret_cast<const bf16x8*>(
                    &patch[(ky * NCOL + site_base + n * 16 + llo + kx) * CPAD + ch * 32 + lhi * 8]);
                #pragma unroll
                for (int m = 0; m < 4; ++m)
                    acc[m][n] = __builtin_amdgcn_mfma_f32_16x16x32_bf16(a[m], bb, acc[m][n], 0, 0, 0);
            }
        }
    }

    // epilogue: D col = lane&15 -> site, row = (lane>>4)*4+r -> co-within-16
    const size_t plane = (size_t)HH * WW;
    const size_t outbase = (size_t)b * COUT * plane + (size_t)y * WW + x0 + site_base;
    #pragma unroll
    for (int m = 0; m < 4; ++m) {
        #pragma unroll
        for (int r = 0; r < 4; ++r) {
            int co = co_base + m * 16 + lhi * 4 + r;
            size_t rowbase = outbase + (size_t)co * plane;
            #pragma unroll
            for (int n = 0; n < 4; ++n) {
                out[rowbase + n * 16 + llo] = acc[m][n][r];
            }
        }
    }
}

extern "C" void kernel_launch(void* const* d_in, const int* in_sizes, int n_in,
                              void* d_out, int out_size, void* d_ws, size_t ws_size,
                              hipStream_t stream) {
    const float* feat  = (const float*)d_in[0];
    const int*   coors = (const int*)d_in[1];
    const float* w     = (const float*)d_in[3];
    float* out = (float*)d_out;

    float* dense = (float*)d_ws;
    const size_t dense_bytes = (size_t)NB * HH * WW * CIN * sizeof(float); // 256 MB
    unsigned short* wt2 = (unsigned short*)((char*)d_ws + dense_bytes);

    const int npts = in_sizes[0] / CIN; // 200000

    hipMemsetAsync(d_ws, 0, dense_bytes, stream);

    hipLaunchKernelGGL(wt_transform, dim3((COUT * 576 + 255) / 256), dim3(256), 0, stream,
                       w, wt2);
    hipLaunchKernelGGL(scatter_kernel, dim3((npts * 64 + 255) / 256), dim3(256), 0, stream,
                       feat, coors, dense, npts);
    hipLaunchKernelGGL(conv_kernel, dim3(NB * HH * (WW / BX)), dim3(256), 0, stream,
                       dense, (const __bf16*)wt2, out);
}